// Round 12
// baseline (307.126 us; speedup 1.0000x reference)
//
#include <hip/hip_runtime.h>
#include <hip/hip_bf16.h>

// ---------------------------------------------------------------------------
// MinigridPPOLSTMAgent forward, round 15 (= round-14 resubmit; infra failure):
// round-9 conv/gemm + MFMA-hybrid LSTM (broadcast-B matvec on the idle
// matrix pipe).
//   T=128, B=256, N=32768, HID=128, NFLAT=1024, NA=7
// Pipeline:
//   P  prep_all   : merged w_ih perm + conv w tables + w_hh MFMA A-fragments
//                   (round-1 verified layout)
//   K1 conv_fused : obs -> featb fp16 (round-9 verbatim)
//   K3 gemm_mfma  : xproj = featb @ wb^T; 128x128, BK=32, dbuf, XCD swizzle
//                   (round-9 verbatim)
//   K4 lstm_mfma  : 256 blocks x 512 thr; gates = whh_frags(64 VGPR) @
//                   broadcast-h via 16 MFMA/wave/step; column-0 scatter to
//                   LDS; float4 gate read + round-6 activation tail.
//   K5 heads      : out[n,8] = hid16 @ [actor;critic].T + b
// ---------------------------------------------------------------------------

#define N_IMG   32768
#define T_LEN   128
#define B_ENV   256
#define HID     128

typedef _Float16 f16x8 __attribute__((ext_vector_type(8)));
typedef _Float16 f16x2 __attribute__((ext_vector_type(2)));
typedef float    f32x4 __attribute__((ext_vector_type(4)));
typedef unsigned short ushort8v __attribute__((ext_vector_type(8)));
typedef unsigned short ushort4v __attribute__((ext_vector_type(4)));

// ---- fast transcendentals: v_exp_f32 / v_rcp_f32 ----
#if defined(__has_builtin)
#if __has_builtin(__builtin_amdgcn_exp2f)
#define FEXP2(x) __builtin_amdgcn_exp2f(x)
#endif
#if __has_builtin(__builtin_amdgcn_rcpf)
#define FRCP(x) __builtin_amdgcn_rcpf(x)
#endif
#endif
#ifndef FEXP2
#define FEXP2(x) exp2f(x)
#endif
#ifndef FRCP
#define FRCP(x) (1.0f / (x))
#endif

__device__ __forceinline__ float sigm_(float x) {
    return FRCP(1.0f + FEXP2(-1.44269504f * x));
}
__device__ __forceinline__ float tanh_(float x) {
    return fmaf(-2.0f, FRCP(1.0f + FEXP2(2.88539008f * x)), 1.0f);
}

__device__ __forceinline__ unsigned short f2h(float x) {
    _Float16 h = (_Float16)x;
    union { _Float16 h; unsigned short u; } un; un.h = h;
    return un.u;
}

#define GLDS16(g, l) __builtin_amdgcn_global_load_lds( \
    (const __attribute__((address_space(1))) unsigned int*)(g), \
    (__attribute__((address_space(3))) unsigned int*)(l), 16, 0, 0)

// ---------------------------------------------------------------------------
// P: merged prep.  blocks [0,2048): w_ih; [2048,2088): conv w; [2088,2344): w_hh
//   whhr (round-1 MFMA A-fragment layout, HW-verified there):
//   idx = (((wv*4 + t4)*4 + kk)*64 + lane)*8 + j
//   row = t4*128 + wv*16 + (lane&15); col = kk*32 + (lane>>4)*8 + j
// ---------------------------------------------------------------------------
__global__ void prep_all(const float* __restrict__ w_ih, unsigned short* __restrict__ wb,
                         const float* __restrict__ w2, const float* __restrict__ w3,
                         unsigned short* __restrict__ wb2g, unsigned short* __restrict__ wb3g,
                         const float* __restrict__ w_hh, unsigned short* __restrict__ whhr)
{
    const int bid = blockIdx.x, tid = threadIdx.x;
    if (bid < 2048) {
        const int idx = bid * 256 + tid;              // < 524288
        const int np = idx >> 10, kk = idx & 1023;
        const int p = kk >> 6, co = kk & 63;
        const int g = np & 3, ci = np >> 2;
        wb[idx] = f2h(w_ih[(g * 128 + ci) * 1024 + co * 16 + p]);
    } else if (bid < 2088) {
        const int t = (bid - 2048) * 256 + tid;       // < 10240
        if (t < 2048) {
            const int j = t & 7, lane = (t >> 3) & 63, f = t >> 9;   // f = ky*2+ct
            const int ky = f >> 1, ct = f & 1;
            const int k = ((lane >> 4) << 3) + j, kx = k >> 4, ci = k & 15;
            wb2g[t] = f2h(w2[(ct * 16 + (lane & 15)) * 64 + ci * 4 + ky * 2 + kx]);
        } else {
            const int u = t - 2048;
            const int j = u & 7, lane = (u >> 3) & 63, f = u >> 9;   // f = ct*4+pos
            const int ct = f >> 2, pos = f & 3;
            const int ci = ((lane >> 4) << 3) + j;
            wb3g[u] = f2h(w3[(ct * 16 + (lane & 15)) * 128 + ci * 4 + pos]);
        }
    } else {
        const int idx = (bid - 2088) * 256 + tid;     // < 65536
        const int j = idx & 7, lane = (idx >> 3) & 63, f = idx >> 9;  // f < 128
        const int kk = f & 3, t4 = (f >> 2) & 3, wv = f >> 4;
        const int row = t4 * 128 + wv * 16 + (lane & 15);
        const int col = kk * 32 + ((lane >> 4) << 3) + j;
        whhr[idx] = f2h(w_hh[row * 128 + col]);
    }
}

// ---------------------------------------------------------------------------
// K1: fused conv. 16 images / block, 2048 blocks, 256 thr (round-9 verbatim).
// ---------------------------------------------------------------------------
__global__ __launch_bounds__(256, 2) void conv_fused(
    const float* __restrict__ obs,
    const float* __restrict__ w1, const float* __restrict__ b1,
    const float* __restrict__ b2, const float* __restrict__ b3,
    const unsigned short* __restrict__ wb2g,
    const unsigned short* __restrict__ wb3g,
    unsigned short* __restrict__ featb)
{
    __shared__ __align__(16) unsigned char u1[25856];   // max(obs 9472, c2s 25856)
    __shared__ __align__(16) unsigned char u2[33024];   // max(c1s 18688, c3s 33024)
    __shared__ float w1s[192];
    __shared__ float b1s[16];

    float* s_obs = (float*)u1;                 // [img][148]
    unsigned short* c2s = (unsigned short*)u1; // [img][pix*32+ci], img stride 808
    unsigned short* c1s = (unsigned short*)u2; // [img][p*16+ci],  img stride 584
    unsigned short* c3s = (unsigned short*)u2; // [img][p*64+co],  img stride 1032

    const int tid = threadIdx.x, lane = tid & 63, wv = tid >> 6;
    const int base = blockIdx.x * 16;

    if (tid < 192) w1s[tid] = w1[tid];
    if (tid < 16)  b1s[tid] = b1[tid];
    for (int i = tid; i < 16 * 147; i += 256) {
        const int im = i / 147, r = i - im * 147;
        s_obs[im * 148 + r] = obs[(size_t)(base + im) * 147 + r];
    }
    __syncthreads();

    // ---- conv1 (fp32 VALU): thread=(img, p) -> c1s[img][p][ci0..15] fp16 ----
    {
        const int img = tid & 15;
        const float* ob = &s_obs[img * 148];
        for (int p = tid >> 4; p < 36; p += 16) {
            const int py = p / 6, px = p % 6;
            float o[12];
#pragma unroll
            for (int ky = 0; ky < 2; ky++)
#pragma unroll
                for (int kx = 0; kx < 2; kx++)
#pragma unroll
                    for (int cc = 0; cc < 3; cc++)
                        o[cc * 4 + ky * 2 + kx] = ob[((py + ky) * 7 + px + kx) * 3 + cc];
            unsigned short res[16];
#pragma unroll
            for (int ci = 0; ci < 16; ci++) {
                float a = b1s[ci];
#pragma unroll
                for (int q = 0; q < 12; q++) a = fmaf(o[q], w1s[ci * 12 + q], a);
                res[ci] = f2h(fmaxf(a, 0.0f));
            }
            *(ushort8v*)&c1s[img * 584 + p * 16]     = *(ushort8v*)&res[0];
            *(ushort8v*)&c1s[img * 584 + p * 16 + 8] = *(ushort8v*)&res[8];
        }
    }
    __syncthreads();

    // ---- conv2 (MFMA): site=(p, cotile); A=weights(M=co16), B=imgs(N=16) ----
    {
        const int ct = wv & 1, par = wv >> 1;
        const int img = lane & 15, kq = lane >> 4;
        f16x8 wA[2];
        wA[0] = *(const f16x8*)&wb2g[(0 + ct) * 512 + lane * 8];   // ky=0
        wA[1] = *(const f16x8*)&wb2g[(2 + ct) * 512 + lane * 8];   // ky=1
        const float4 b2v = *(const float4*)&b2[ct * 16 + kq * 4];
#pragma unroll 2
        for (int p = par; p < 25; p += 2) {
            const int py = p / 5, px = p % 5;
            f32x4 acc = {0.f, 0.f, 0.f, 0.f};
#pragma unroll
            for (int ky = 0; ky < 2; ky++) {
                const int pix = (py + ky) * 6 + px + (kq >> 1);
                const f16x8 bv = *(const f16x8*)&c1s[img * 584 + pix * 16 + (kq & 1) * 8];
                acc = __builtin_amdgcn_mfma_f32_16x16x32_f16(wA[ky], bv, acc, 0, 0, 0);
            }
            unsigned short r4[4];
            r4[0] = f2h(fmaxf(acc[0] + b2v.x, 0.0f));
            r4[1] = f2h(fmaxf(acc[1] + b2v.y, 0.0f));
            r4[2] = f2h(fmaxf(acc[2] + b2v.z, 0.0f));
            r4[3] = f2h(fmaxf(acc[3] + b2v.w, 0.0f));
            *(ushort4v*)&c2s[img * 808 + p * 32 + ct * 16 + kq * 4] = *(ushort4v*)&r4[0];
        }
    }
    __syncthreads();

    // ---- conv3 (MFMA): wave = cotile (4 x 16 co); 16 pixel-sites each ----
    {
        const int ct = wv;
        const int img = lane & 15, kq = lane >> 4;
        f16x8 wA3[4];
#pragma unroll
        for (int pos = 0; pos < 4; pos++)
            wA3[pos] = *(const f16x8*)&wb3g[(ct * 4 + pos) * 512 + lane * 8];
        const float4 b3v = *(const float4*)&b3[ct * 16 + kq * 4];
#pragma unroll 4
        for (int p = 0; p < 16; p++) {
            const int py = p >> 2, px = p & 3;
            f32x4 acc = {0.f, 0.f, 0.f, 0.f};
#pragma unroll
            for (int pos = 0; pos < 4; pos++) {
                const int pix = (py + (pos >> 1)) * 5 + px + (pos & 1);
                const f16x8 bv = *(const f16x8*)&c2s[img * 808 + pix * 32 + kq * 8];
                acc = __builtin_amdgcn_mfma_f32_16x16x32_f16(wA3[pos], bv, acc, 0, 0, 0);
            }
            unsigned short r4[4];
            r4[0] = f2h(fmaxf(acc[0] + b3v.x, 0.0f));
            r4[1] = f2h(fmaxf(acc[1] + b3v.y, 0.0f));
            r4[2] = f2h(fmaxf(acc[2] + b3v.z, 0.0f));
            r4[3] = f2h(fmaxf(acc[3] + b3v.w, 0.0f));
            *(ushort4v*)&c3s[img * 1032 + p * 64 + ct * 16 + kq * 4] = *(ushort4v*)&r4[0];
        }
    }
    __syncthreads();

    // ---- dump c3s -> featb (feat row already in permuted k'=p*64+co order) ----
#pragma unroll
    for (int i = 0; i < 8; i++) {
        const int gi = i * 2048 + tid * 8;
        const int img = gi >> 10, flat = gi & 1023;
        *(ushort8v*)&featb[(size_t)(base + img) * 1024 + flat] =
            *(const ushort8v*)&c3s[img * 1032 + flat];
    }
}

// ---------------------------------------------------------------------------
// K3: xproj[32768,512] = featb @ wb^T (round-9 verbatim: 128x128, BK=32,
//   dbuf stage-ahead, XCD-chunked swizzle).
// ---------------------------------------------------------------------------
__global__ __launch_bounds__(256, 2) void gemm_xproj_mfma(
    const unsigned short* __restrict__ A,
    const unsigned short* __restrict__ W,
    float* __restrict__ C)
{
    __shared__ unsigned short As[2][128 * 32];
    __shared__ unsigned short Bs[2][128 * 32];

    const int tid  = threadIdx.x;
    // XCD-chunked swizzle: nwg=1024, NXCD=8, chunk=128
    const int wg = (blockIdx.x & 7) * 128 + (blockIdx.x >> 3);
    const int bx = wg & 3;
    const int by = wg >> 2;
    const int m0 = by * 128, n0 = bx * 128;
    const int lane = tid & 63, wave = tid >> 6;
    const int wm = (wave >> 1) * 64, wn = (wave & 1) * 64;
    const int srow = tid >> 2, sseg = tid & 3;

    const unsigned short* Ag = A + (size_t)(m0 + srow) * 1024 + sseg * 8;
    const unsigned short* Wg = W + (size_t)(n0 + srow) * 1024 + sseg * 8;

    f32x4 acc[4][4];
#pragma unroll
    for (int i = 0; i < 4; i++)
#pragma unroll
        for (int j = 0; j < 4; j++) acc[i][j] = (f32x4){0.f, 0.f, 0.f, 0.f};

    const int fr = lane & 15, fq = lane >> 4;

#define STAGEK(bb, k0) do {                                                \
        GLDS16(Ag + (k0),             (char*)&As[bb][0] + tid * 16);       \
        GLDS16(Ag + (k0) + 64 * 1024, (char*)&As[bb][0] + tid * 16 + 4096);\
        GLDS16(Wg + (k0),             (char*)&Bs[bb][0] + tid * 16);       \
        GLDS16(Wg + (k0) + 64 * 1024, (char*)&Bs[bb][0] + tid * 16 + 4096);\
    } while (0)

    STAGEK(0, 0);
    asm volatile("s_waitcnt vmcnt(0)" ::: "memory");
    __syncthreads();

    int cur = 0;
    for (int ks = 0; ks < 32; ks++) {
        if (ks + 1 < 32) STAGEK(cur ^ 1, (ks + 1) * 32);   // fly under MFMA

        f16x8 af[4], bfv[4];
#pragma unroll
        for (int i = 0; i < 4; i++)
            af[i] = *(const f16x8*)&As[cur][(wm + i * 16 + fr) * 32 + fq * 8];
#pragma unroll
        for (int j = 0; j < 4; j++)
            bfv[j] = *(const f16x8*)&Bs[cur][(wn + j * 16 + fr) * 32 + fq * 8];
#pragma unroll
        for (int i = 0; i < 4; i++)
#pragma unroll
            for (int j = 0; j < 4; j++)
                acc[i][j] = __builtin_amdgcn_mfma_f32_16x16x32_f16(af[i], bfv[j], acc[i][j], 0, 0, 0);

        asm volatile("s_waitcnt vmcnt(0)" ::: "memory");
        __syncthreads();
        cur ^= 1;
    }
#undef STAGEK

    const int cr = fq * 4, cc = fr;
#pragma unroll
    for (int i = 0; i < 4; i++) {
#pragma unroll
        for (int j = 0; j < 4; j++) {
            float* cp = &C[(size_t)(m0 + wm + i * 16 + cr) * 512 + (n0 + wn + j * 16 + cc)];
#pragma unroll
            for (int r = 0; r < 4; r++)
                cp[(size_t)r * 512] = acc[i][j][r];
        }
    }
}

// ---------------------------------------------------------------------------
// K4: MFMA-hybrid LSTM.  256 blocks (1 elem each) x 512 thr (8 waves).
//   gates[512] = w_hh @ h via MFMA with BROADCAST B (all 16 columns = h):
//   wastes 15/16 of the matrix-pipe FLOPs, but that pipe was idle and it
//   removes ~200 VALU slots/thread/step from the round-6 kernel.
//   A-frags (af[t4][kk], 64 VGPR) + B-broadcast + C col-0 mapping reuse the
//   round-1 HW-verified layouts.  Column-0 lanes (fr==0) scatter the 64
//   gate sums to gate_lds[cell][gate]; after a mid-barrier every thread
//   reads its cell's float4 (i,f,g,o) and runs the round-6 activation tail.
// ---------------------------------------------------------------------------
__global__ __launch_bounds__(512) __attribute__((amdgpu_waves_per_eu(2, 2)))
void lstm_mfma(
    const float* __restrict__ xproj, const float* __restrict__ done,
    const float* __restrict__ h0, const float* __restrict__ c0,
    const unsigned short* __restrict__ whhr,
    const float* __restrict__ b_ih, const float* __restrict__ b_hh,
    unsigned short* __restrict__ hid16, float* __restrict__ out)
{
    const int b    = blockIdx.x;
    const int tid  = threadIdx.x;
    const int lane = tid & 63, wv = tid >> 6;
    const int fr   = lane & 15, q = lane >> 4;
    const int ci   = tid >> 2;      // cell for activation phase (0..127)
    const int s    = tid & 3;

    __shared__ __align__(16) _Float16 hbuf[2][HID];
    __shared__ __align__(16) float gate_lds[HID * 4];   // [cell][gate i,f,g,o]

    // ---- resident A fragments: 4 gate-tiles x 4 k-steps = 64 VGPRs ----
    f16x8 af[4][4];
#pragma unroll
    for (int t4 = 0; t4 < 4; t4++)
#pragma unroll
        for (int kk = 0; kk < 4; kk++)
            af[t4][kk] = *(const f16x8*)&whhr[(size_t)(((wv * 4 + t4) * 4 + kk) * 64 + lane) * 8];

    // ---- per-thread bias for the 4 gates of cell ci ----
    float bias4[4];
#pragma unroll
    for (int g = 0; g < 4; g++)
        bias4[g] = b_ih[g * 128 + ci] + b_hh[g * 128 + ci];

    // ---- state ----
    float c = c0[b * HID + ci];
    float h = 0.0f;
    float dcur = done[b];
    if (tid < HID)
        hbuf[0][tid] = (_Float16)(h0[b * HID + tid] * (1.0f - dcur));

    // step-0 gate input: xproj rows pre-permuted to n' = ci*4 + g -> float4
    float xpb[4];
    {
        const float4 v = *(const float4*)&xproj[(size_t)b * 512 + ci * 4];
        xpb[0] = v.x + bias4[0]; xpb[1] = v.y + bias4[1];
        xpb[2] = v.z + bias4[2]; xpb[3] = v.w + bias4[3];
    }
    __syncthreads();

    int p = 0;
    for (int t = 0; t < T_LEN; t++) {
        // ---- prefetch next-step xproj/done (consumed after the barrier) ----
        const int tn = (t + 1 < T_LEN) ? t + 1 : t;
        const float4 nv = *(const float4*)&xproj[((size_t)tn * B_ENV + b) * 512 + ci * 4];
        const float dnn = done[tn * B_ENV + b];

        // ---- B fragments: broadcast h (all 16 cols identical) ----
        // lane layout for 16x16x32 B: col=lane&15 (ignored), k=(lane>>4)*8+j
        f16x8 bf[4];
#pragma unroll
        for (int kk = 0; kk < 4; kk++)
            bf[kk] = *(const f16x8*)&hbuf[p][kk * 32 + q * 8];

        // ---- 16 MFMAs: acc[t4] accumulates over kk ----
        f32x4 acc[4];
#pragma unroll
        for (int t4 = 0; t4 < 4; t4++) acc[t4] = (f32x4){0.f, 0.f, 0.f, 0.f};
#pragma unroll
        for (int kk = 0; kk < 4; kk++)
#pragma unroll
            for (int t4 = 0; t4 < 4; t4++)
                acc[t4] = __builtin_amdgcn_mfma_f32_16x16x32_f16(af[t4][kk], bf[kk], acc[t4], 0, 0, 0);

        // ---- scatter column 0: C layout col=lane&15, row=(lane>>4)*4+r ----
        // gate row (tile t4) = t4*128 + wv*16 + q*4 + r  ->  cell wv*16+q*4+r
        if (fr == 0) {
#pragma unroll
            for (int t4 = 0; t4 < 4; t4++)
#pragma unroll
                for (int r = 0; r < 4; r++)
                    gate_lds[(wv * 16 + q * 4 + r) * 4 + t4] = acc[t4][r];
        }
        __syncthreads();

        // ---- activation tail (round-6 form; 4 redundant lanes per cell) ----
        const float4 g4 = *(const float4*)&gate_lds[ci * 4];
        const float gi = sigm_(g4.x + xpb[0]);
        const float gf = sigm_(g4.y + xpb[1]);
        const float gg = tanh_(g4.z + xpb[2]);
        const float go = sigm_(g4.w + xpb[3]);
        const float m = 1.0f - dcur;
        c = fmaf(gf, c * m, gi * gg);
        h = go * tanh_(c);

        if (s == 0) {
            hid16[((size_t)t * B_ENV + b) * HID + ci] = f2h(h);
            hbuf[p ^ 1][ci] = (_Float16)(h * (1.0f - dnn));
        }

        xpb[0] = nv.x + bias4[0]; xpb[1] = nv.y + bias4[1];
        xpb[2] = nv.z + bias4[2]; xpb[3] = nv.w + bias4[3];
        dcur = dnn; p ^= 1;
        __syncthreads();
    }

    if (s == 0) {
        out[262144 + b * HID + ci] = h;
        out[294912 + b * HID + ci] = c;
    }
}

// ---------------------------------------------------------------------------
// K5: heads. out[n][0..6] = actor, out[n][7] = critic. 32 rows / block.
// ---------------------------------------------------------------------------
__global__ __launch_bounds__(256, 2) void heads_kernel(
    const unsigned short* __restrict__ hid16,
    const float* __restrict__ aw, const float* __restrict__ ab,
    const float* __restrict__ cw, const float* __restrict__ cb,
    float* __restrict__ out)
{
    __shared__ float hs[32 * 129];
    __shared__ float ws[8 * 130];
    __shared__ float bs[8];

    const int tid = threadIdx.x;
    const int n0 = blockIdx.x * 32;

    for (int i = tid; i < 1024; i += 256) {
        const int r = i >> 7, k = i & 127;
        ws[r * 130 + k] = (r < 7) ? aw[r * 128 + k] : cw[k];
    }
    if (tid < 8) bs[tid] = (tid < 7) ? ab[tid] : cb[0];
    // staged fp16 -> fp32 conversion, 8 halves per thread iteration
    for (int i = tid; i < 512; i += 256) {
        const int r = i >> 4, k8 = (i & 15) * 8;
        const ushort8v v = *(const ushort8v*)&hid16[(size_t)(n0 + r) * 128 + k8];
#pragma unroll
        for (int q = 0; q < 8; q++) {
            union { unsigned short u; _Float16 h; } un; un.u = v[q];
            hs[r * 129 + k8 + q] = (float)un.h;
        }
    }
    __syncthreads();

    const int r = tid >> 3, jj = tid & 7;
    float acc = bs[jj];
    const float* hp = &hs[r * 129];
    const float* wp = &ws[jj * 130];
#pragma unroll
    for (int k = 0; k < 128; k++) acc = fmaf(hp[k], wp[k], acc);
    out[(size_t)(n0 + r) * 8 + jj] = acc;
}

// ---------------------------------------------------------------------------
extern "C" void kernel_launch(void* const* d_in, const int* in_sizes, int n_in,
                              void* d_out, int out_size, void* d_ws, size_t ws_size,
                              hipStream_t stream)
{
    (void)in_sizes; (void)n_in; (void)out_size; (void)ws_size;

    const float* obs  = (const float*)d_in[0];
    const float* done = (const float*)d_in[1];
    const float* h0   = (const float*)d_in[2];
    const float* c0   = (const float*)d_in[3];
    const float* w1   = (const float*)d_in[4];
    const float* b1   = (const float*)d_in[5];
    const float* w2   = (const float*)d_in[6];
    const float* b2   = (const float*)d_in[7];
    const float* w3   = (const float*)d_in[8];
    const float* b3   = (const float*)d_in[9];
    const float* w_ih = (const float*)d_in[10];
    const float* w_hh = (const float*)d_in[11];
    const float* b_ih = (const float*)d_in[12];
    const float* b_hh = (const float*)d_in[13];
    const float* aw   = (const float*)d_in[14];
    const float* ab   = (const float*)d_in[15];
    const float* cw   = (const float*)d_in[16];
    const float* cb   = (const float*)d_in[17];
    float* out = (float*)d_out;

    unsigned short* featb = (unsigned short*)d_ws;     // 33,554,432 u16
    unsigned short* wb    = featb + 33554432ull;       //    524,288 u16
    unsigned short* wb2g  = wb    + 524288ull;         //      2,048 u16
    unsigned short* wb3g  = wb2g  + 2048ull;           //      8,192 u16
    float* xproj = (float*)(wb3g + 8192ull + 2048ull); // align pad; 16,777,216 f32
    unsigned short* hid16 = (unsigned short*)(xproj + 16777216ull); // 4,194,304 u16
    unsigned short* whhr  = hid16 + 4194304ull;        // 65,536 u16

    prep_all<<<2344, 256, 0, stream>>>(w_ih, wb, w2, w3, wb2g, wb3g, w_hh, whhr);
    conv_fused<<<2048, 256, 0, stream>>>(obs, w1, b1, b2, b3, wb2g, wb3g, featb);
    gemm_xproj_mfma<<<1024, 256, 0, stream>>>(featb, wb, xproj);
    lstm_mfma<<<256, 512, 0, stream>>>(xproj, done, h0, c0, whhr, b_ih, b_hh, hid16, out);
    heads_kernel<<<1024, 256, 0, stream>>>(hid16, aw, ab, cw, cb, out);
}

// Round 13
// 269.461 us; speedup vs baseline: 1.1398x; 1.1398x over previous
//
#include <hip/hip_runtime.h>
#include <hip/hip_bf16.h>

// ---------------------------------------------------------------------------
// MinigridPPOLSTMAgent forward, round 16: round-9 config (best: 269.2 us)
// with gemm N-tile widened 128->256 (halves featb A-refetch traffic).
//   T=128, B=256, N=32768, HID=128, NFLAT=1024, NA=7
// Pipeline:
//   P  prep_all   : merged w_ih perm + conv w tables + w_hh per-thread blocks
//   K1 conv_fused : obs -> featb fp16 (round-9 verbatim)
//   K3 gemm_mfma  : xproj = featb @ wb^T; 128x256 tile, BK=32, dbuf,
//                   512 thr (8 waves 2Mx4N), 2 blocks/CU, XCD swizzle.
//                   A-tile now read by 2 blocks (was 4): 256->128 MB traffic.
//   K4 lstm_bfly  : round-6/9 winner verbatim (92 us floor; r7/r8/r14
//                   restructures all regressed).
//   K5 heads      : out[n,8] = hid16 @ [actor;critic].T + b
// ---------------------------------------------------------------------------

#define N_IMG   32768
#define T_LEN   128
#define B_ENV   256
#define HID     128

typedef _Float16 f16x8 __attribute__((ext_vector_type(8)));
typedef _Float16 f16x2 __attribute__((ext_vector_type(2)));
typedef float    f32x4 __attribute__((ext_vector_type(4)));
typedef unsigned short ushort8v __attribute__((ext_vector_type(8)));
typedef unsigned short ushort4v __attribute__((ext_vector_type(4)));

// ---- fast transcendentals: v_exp_f32 / v_rcp_f32 ----
#if defined(__has_builtin)
#if __has_builtin(__builtin_amdgcn_exp2f)
#define FEXP2(x) __builtin_amdgcn_exp2f(x)
#endif
#if __has_builtin(__builtin_amdgcn_rcpf)
#define FRCP(x) __builtin_amdgcn_rcpf(x)
#endif
#endif
#ifndef FEXP2
#define FEXP2(x) exp2f(x)
#endif
#ifndef FRCP
#define FRCP(x) (1.0f / (x))
#endif

__device__ __forceinline__ float sigm_(float x) {
    return FRCP(1.0f + FEXP2(-1.44269504f * x));
}
__device__ __forceinline__ float tanh_(float x) {
    return fmaf(-2.0f, FRCP(1.0f + FEXP2(2.88539008f * x)), 1.0f);
}

__device__ __forceinline__ unsigned short f2h(float x) {
    _Float16 h = (_Float16)x;
    union { _Float16 h; unsigned short u; } un; un.h = h;
    return un.u;
}

#if defined(__has_builtin)
#if __has_builtin(__builtin_amdgcn_fdot2)
#define HAVE_FDOT2 1
#endif
#endif

__device__ __forceinline__ float dot2_(f16x2 a, f16x2 b, float c) {
#ifdef HAVE_FDOT2
    return __builtin_amdgcn_fdot2(a, b, c, false);
#else
    c = fmaf((float)a[0], (float)b[0], c);
    return fmaf((float)a[1], (float)b[1], c);
#endif
}

// literal-index pair extraction from f16x8 (shufflevector needs constants)
#define P0(v) __builtin_shufflevector(v, v, 0, 1)
#define P1(v) __builtin_shufflevector(v, v, 2, 3)
#define P2(v) __builtin_shufflevector(v, v, 4, 5)
#define P3(v) __builtin_shufflevector(v, v, 6, 7)

// quad butterfly sum via DPP quad_perm (xor1 = 0xB1, xor2 = 0x4E): pure VALU.
__device__ __forceinline__ float bfly_sum4(float x) {
    int y = __builtin_amdgcn_update_dpp(0, __float_as_int(x), 0xB1, 0xF, 0xF, true);
    x += __int_as_float(y);
    y = __builtin_amdgcn_update_dpp(0, __float_as_int(x), 0x4E, 0xF, 0xF, true);
    return x + __int_as_float(y);
}

#define GLDS16(g, l) __builtin_amdgcn_global_load_lds( \
    (const __attribute__((address_space(1))) unsigned int*)(g), \
    (__attribute__((address_space(3))) unsigned int*)(l), 16, 0, 0)

// ---------------------------------------------------------------------------
// P: merged prep.  blocks [0,2048): w_ih; [2048,2088): conv w; [2088,2344): w_hh
//   whhr (round-6 layout): thr = idx>>7 owns 128 halfs:
//   whhr[thr*128 + g*32 + k] = w_hh[(g*128+(thr>>2))*128 + (thr&3)*32 + k]
// ---------------------------------------------------------------------------
__global__ void prep_all(const float* __restrict__ w_ih, unsigned short* __restrict__ wb,
                         const float* __restrict__ w2, const float* __restrict__ w3,
                         unsigned short* __restrict__ wb2g, unsigned short* __restrict__ wb3g,
                         const float* __restrict__ w_hh, unsigned short* __restrict__ whhr)
{
    const int bid = blockIdx.x, tid = threadIdx.x;
    if (bid < 2048) {
        const int idx = bid * 256 + tid;              // < 524288
        const int np = idx >> 10, kk = idx & 1023;
        const int p = kk >> 6, co = kk & 63;
        const int g = np & 3, ci = np >> 2;
        wb[idx] = f2h(w_ih[(g * 128 + ci) * 1024 + co * 16 + p]);
    } else if (bid < 2088) {
        const int t = (bid - 2048) * 256 + tid;       // < 10240
        if (t < 2048) {
            const int j = t & 7, lane = (t >> 3) & 63, f = t >> 9;   // f = ky*2+ct
            const int ky = f >> 1, ct = f & 1;
            const int k = ((lane >> 4) << 3) + j, kx = k >> 4, ci = k & 15;
            wb2g[t] = f2h(w2[(ct * 16 + (lane & 15)) * 64 + ci * 4 + ky * 2 + kx]);
        } else {
            const int u = t - 2048;
            const int j = u & 7, lane = (u >> 3) & 63, f = u >> 9;   // f = ct*4+pos
            const int ct = f >> 2, pos = f & 3;
            const int ci = ((lane >> 4) << 3) + j;
            wb3g[u] = f2h(w3[(ct * 16 + (lane & 15)) * 128 + ci * 4 + pos]);
        }
    } else {
        const int idx = (bid - 2088) * 256 + tid;     // < 65536
        const int thr = idx >> 7, r = idx & 127;
        const int g = r >> 5, k = r & 31;
        const int ci = thr >> 2, s = thr & 3;
        whhr[idx] = f2h(w_hh[(g * 128 + ci) * 128 + s * 32 + k]);
    }
}

// ---------------------------------------------------------------------------
// K1: fused conv. 16 images / block, 2048 blocks, 256 thr (round-9 verbatim).
// ---------------------------------------------------------------------------
__global__ __launch_bounds__(256, 2) void conv_fused(
    const float* __restrict__ obs,
    const float* __restrict__ w1, const float* __restrict__ b1,
    const float* __restrict__ b2, const float* __restrict__ b3,
    const unsigned short* __restrict__ wb2g,
    const unsigned short* __restrict__ wb3g,
    unsigned short* __restrict__ featb)
{
    __shared__ __align__(16) unsigned char u1[25856];   // max(obs 9472, c2s 25856)
    __shared__ __align__(16) unsigned char u2[33024];   // max(c1s 18688, c3s 33024)
    __shared__ float w1s[192];
    __shared__ float b1s[16];

    float* s_obs = (float*)u1;                 // [img][148]
    unsigned short* c2s = (unsigned short*)u1; // [img][pix*32+ci], img stride 808
    unsigned short* c1s = (unsigned short*)u2; // [img][p*16+ci],  img stride 584
    unsigned short* c3s = (unsigned short*)u2; // [img][p*64+co],  img stride 1032

    const int tid = threadIdx.x, lane = tid & 63, wv = tid >> 6;
    const int base = blockIdx.x * 16;

    if (tid < 192) w1s[tid] = w1[tid];
    if (tid < 16)  b1s[tid] = b1[tid];
    for (int i = tid; i < 16 * 147; i += 256) {
        const int im = i / 147, r = i - im * 147;
        s_obs[im * 148 + r] = obs[(size_t)(base + im) * 147 + r];
    }
    __syncthreads();

    // ---- conv1 (fp32 VALU): thread=(img, p) -> c1s[img][p][ci0..15] fp16 ----
    {
        const int img = tid & 15;
        const float* ob = &s_obs[img * 148];
        for (int p = tid >> 4; p < 36; p += 16) {
            const int py = p / 6, px = p % 6;
            float o[12];
#pragma unroll
            for (int ky = 0; ky < 2; ky++)
#pragma unroll
                for (int kx = 0; kx < 2; kx++)
#pragma unroll
                    for (int cc = 0; cc < 3; cc++)
                        o[cc * 4 + ky * 2 + kx] = ob[((py + ky) * 7 + px + kx) * 3 + cc];
            unsigned short res[16];
#pragma unroll
            for (int ci = 0; ci < 16; ci++) {
                float a = b1s[ci];
#pragma unroll
                for (int q = 0; q < 12; q++) a = fmaf(o[q], w1s[ci * 12 + q], a);
                res[ci] = f2h(fmaxf(a, 0.0f));
            }
            *(ushort8v*)&c1s[img * 584 + p * 16]     = *(ushort8v*)&res[0];
            *(ushort8v*)&c1s[img * 584 + p * 16 + 8] = *(ushort8v*)&res[8];
        }
    }
    __syncthreads();

    // ---- conv2 (MFMA): site=(p, cotile); A=weights(M=co16), B=imgs(N=16) ----
    {
        const int ct = wv & 1, par = wv >> 1;
        const int img = lane & 15, kq = lane >> 4;
        f16x8 wA[2];
        wA[0] = *(const f16x8*)&wb2g[(0 + ct) * 512 + lane * 8];   // ky=0
        wA[1] = *(const f16x8*)&wb2g[(2 + ct) * 512 + lane * 8];   // ky=1
        const float4 b2v = *(const float4*)&b2[ct * 16 + kq * 4];
#pragma unroll 2
        for (int p = par; p < 25; p += 2) {
            const int py = p / 5, px = p % 5;
            f32x4 acc = {0.f, 0.f, 0.f, 0.f};
#pragma unroll
            for (int ky = 0; ky < 2; ky++) {
                const int pix = (py + ky) * 6 + px + (kq >> 1);
                const f16x8 bv = *(const f16x8*)&c1s[img * 584 + pix * 16 + (kq & 1) * 8];
                acc = __builtin_amdgcn_mfma_f32_16x16x32_f16(wA[ky], bv, acc, 0, 0, 0);
            }
            unsigned short r4[4];
            r4[0] = f2h(fmaxf(acc[0] + b2v.x, 0.0f));
            r4[1] = f2h(fmaxf(acc[1] + b2v.y, 0.0f));
            r4[2] = f2h(fmaxf(acc[2] + b2v.z, 0.0f));
            r4[3] = f2h(fmaxf(acc[3] + b2v.w, 0.0f));
            *(ushort4v*)&c2s[img * 808 + p * 32 + ct * 16 + kq * 4] = *(ushort4v*)&r4[0];
        }
    }
    __syncthreads();

    // ---- conv3 (MFMA): wave = cotile (4 x 16 co); 16 pixel-sites each ----
    {
        const int ct = wv;
        const int img = lane & 15, kq = lane >> 4;
        f16x8 wA3[4];
#pragma unroll
        for (int pos = 0; pos < 4; pos++)
            wA3[pos] = *(const f16x8*)&wb3g[(ct * 4 + pos) * 512 + lane * 8];
        const float4 b3v = *(const float4*)&b3[ct * 16 + kq * 4];
#pragma unroll 4
        for (int p = 0; p < 16; p++) {
            const int py = p >> 2, px = p & 3;
            f32x4 acc = {0.f, 0.f, 0.f, 0.f};
#pragma unroll
            for (int pos = 0; pos < 4; pos++) {
                const int pix = (py + (pos >> 1)) * 5 + px + (pos & 1);
                const f16x8 bv = *(const f16x8*)&c2s[img * 808 + pix * 32 + kq * 8];
                acc = __builtin_amdgcn_mfma_f32_16x16x32_f16(wA3[pos], bv, acc, 0, 0, 0);
            }
            unsigned short r4[4];
            r4[0] = f2h(fmaxf(acc[0] + b3v.x, 0.0f));
            r4[1] = f2h(fmaxf(acc[1] + b3v.y, 0.0f));
            r4[2] = f2h(fmaxf(acc[2] + b3v.z, 0.0f));
            r4[3] = f2h(fmaxf(acc[3] + b3v.w, 0.0f));
            *(ushort4v*)&c3s[img * 1032 + p * 64 + ct * 16 + kq * 4] = *(ushort4v*)&r4[0];
        }
    }
    __syncthreads();

    // ---- dump c3s -> featb (feat row already in permuted k'=p*64+co order) ----
#pragma unroll
    for (int i = 0; i < 8; i++) {
        const int gi = i * 2048 + tid * 8;
        const int img = gi >> 10, flat = gi & 1023;
        *(ushort8v*)&featb[(size_t)(base + img) * 1024 + flat] =
            *(const ushort8v*)&c3s[img * 1032 + flat];
    }
}

// ---------------------------------------------------------------------------
// K3: xproj[32768,512] = featb[32768,1024]_f16 @ wb[512,1024]_f16^T (fp32 out)
//   128x256 tile, BK=32, 512 thr (8 waves: 2M x 4N), double-buffered
//   stage-ahead, vmcnt(0)+1 barrier per K-step.  A-tile read by 2 blocks
//   (was 4) -> featb refetch traffic 256->128 MB.  LDS 48 KB, acc 4x4/wave
//   (64 VGPR, same as round 9); launch_bounds(512,2) caps VGPR at 128.
//   XCD-chunked swizzle: nwg=512, chunk 64; A-sharing neighbors same XCD.
// ---------------------------------------------------------------------------
__global__ __launch_bounds__(512, 2) void gemm_xproj_mfma(
    const unsigned short* __restrict__ A,
    const unsigned short* __restrict__ W,
    float* __restrict__ C)
{
    __shared__ unsigned short As[2][128 * 32];   // 16 KB
    __shared__ unsigned short Bs[2][256 * 32];   // 32 KB

    const int tid  = threadIdx.x;
    // XCD-chunked swizzle: nwg=512, NXCD=8, chunk=64 (bijective: 512%8==0)
    const int wg = (blockIdx.x & 7) * 64 + (blockIdx.x >> 3);
    const int bx = wg & 1;            // N tile (2 x 256)
    const int by = wg >> 1;           // M tile (256 x 128)
    const int m0 = by * 128, n0 = bx * 256;
    const int lane = tid & 63, wave = tid >> 6;
    const int wm = (wave >> 2) * 64;  // 2 M-halves
    const int wn = (wave & 3) * 64;   // 4 N-quarters
    const int srow = tid >> 2, sseg = tid & 3;   // srow 0..127

    const unsigned short* Ag  = A + (size_t)(m0 + srow) * 1024 + sseg * 8;
    const unsigned short* Wg  = W + (size_t)(n0 + srow) * 1024 + sseg * 8;
    const unsigned short* Wg2 = Wg + 128 * 1024;   // rows n0+128 .. n0+255

    f32x4 acc[4][4];
#pragma unroll
    for (int i = 0; i < 4; i++)
#pragma unroll
        for (int j = 0; j < 4; j++) acc[i][j] = (f32x4){0.f, 0.f, 0.f, 0.f};

    const int fr = lane & 15, fq = lane >> 4;

#define STAGEK(bb, k0) do {                                                 \
        GLDS16(Ag  + (k0), (char*)&As[bb][0] + tid * 16);                   \
        GLDS16(Wg  + (k0), (char*)&Bs[bb][0] + tid * 16);                   \
        GLDS16(Wg2 + (k0), (char*)&Bs[bb][0] + tid * 16 + 8192);            \
    } while (0)

    STAGEK(0, 0);
    asm volatile("s_waitcnt vmcnt(0)" ::: "memory");
    __syncthreads();

    int cur = 0;
    for (int ks = 0; ks < 32; ks++) {
        if (ks + 1 < 32) STAGEK(cur ^ 1, (ks + 1) * 32);   // fly under MFMA

        f16x8 af[4], bfv[4];
#pragma unroll
        for (int i = 0; i < 4; i++)
            af[i] = *(const f16x8*)&As[cur][(wm + i * 16 + fr) * 32 + fq * 8];
#pragma unroll
        for (int j = 0; j < 4; j++)
            bfv[j] = *(const f16x8*)&Bs[cur][(wn + j * 16 + fr) * 32 + fq * 8];
#pragma unroll
        for (int i = 0; i < 4; i++)
#pragma unroll
            for (int j = 0; j < 4; j++)
                acc[i][j] = __builtin_amdgcn_mfma_f32_16x16x32_f16(af[i], bfv[j], acc[i][j], 0, 0, 0);

        asm volatile("s_waitcnt vmcnt(0)" ::: "memory");
        __syncthreads();
        cur ^= 1;
    }
#undef STAGEK

    const int cr = fq * 4, cc = fr;
#pragma unroll
    for (int i = 0; i < 4; i++) {
#pragma unroll
        for (int j = 0; j < 4; j++) {
            float* cp = &C[(size_t)(m0 + wm + i * 16 + cr) * 512 + (n0 + wn + j * 16 + cc)];
#pragma unroll
            for (int r = 0; r < 4; r++)
                cp[(size_t)r * 512] = acc[i][j][r];
        }
    }
}

// ---------------------------------------------------------------------------
// K4: 1-barrier butterfly LSTM (round-6/9 winner, verbatim — 92 us floor).
// ---------------------------------------------------------------------------
__global__ __launch_bounds__(512) __attribute__((amdgpu_waves_per_eu(2, 2)))
void lstm_bfly(
    const float* __restrict__ xproj, const float* __restrict__ done,
    const float* __restrict__ h0, const float* __restrict__ c0,
    const unsigned short* __restrict__ whhr,
    const float* __restrict__ b_ih, const float* __restrict__ b_hh,
    unsigned short* __restrict__ hid16, float* __restrict__ out)
{
    const int b   = blockIdx.x;
    const int tid = threadIdx.x;
    const int ci  = tid >> 2;        // cell 0..127
    const int s   = tid & 3;         // k-quarter 0..3

    __shared__ __align__(16) _Float16 hbuf[2][HID];

    // ---- resident weights: w[g][i] = w_hh[g*128+ci][s*32 + i*8 .. +8) ----
    f16x8 w[4][4];
    {
        const unsigned short* wp = whhr + (size_t)tid * 128;
#pragma unroll
        for (int g = 0; g < 4; g++)
#pragma unroll
            for (int i = 0; i < 4; i++)
                w[g][i] = *(const f16x8*)&wp[g * 32 + i * 8];
    }
    // ---- this lane's gate row (original order): n = s*128 + ci ----
    const float bias_l = b_ih[s * 128 + ci] + b_hh[s * 128 + ci];

    // ---- redundant cell state (identical across the 4 lanes of a cell) ----
    float c = c0[b * HID + ci];
    float h = h0[b * HID + ci];
    float dcur = done[b];

    if (tid < HID)
        hbuf[0][tid] = (_Float16)(h0[b * HID + tid] * (1.0f - dcur));

    // step-0 gate input (row ci*4+s thanks to the prep row-perm)
    float xq = bias_l + xproj[(size_t)b * 512 + ci * 4 + s];
    __syncthreads();

// one pair-block of the dot: 1 ds_read_b128 + 16 dot2 into chains c0..c3
#define DOTBLK(i, c0_, c1_, c2_, c3_)                                           \
    {                                                                           \
        const f16x8 hv8 = *(const f16x8*)&hbuf[p][s * 32 + (i) * 8];            \
        const f16x2 hp0 = P0(hv8), hp1 = P1(hv8), hp2 = P2(hv8), hp3 = P3(hv8); \
        c0_ = dot2_(P0(w[0][i]), hp0, c0_); c0_ = dot2_(P1(w[0][i]), hp1, c0_); \
        c0_ = dot2_(P2(w[0][i]), hp2, c0_); c0_ = dot2_(P3(w[0][i]), hp3, c0_); \
        c1_ = dot2_(P0(w[1][i]), hp0, c1_); c1_ = dot2_(P1(w[1][i]), hp1, c1_); \
        c1_ = dot2_(P2(w[1][i]), hp2, c1_); c1_ = dot2_(P3(w[1][i]), hp3, c1_); \
        c2_ = dot2_(P0(w[2][i]), hp0, c2_); c2_ = dot2_(P1(w[2][i]), hp1, c2_); \
        c2_ = dot2_(P2(w[2][i]), hp2, c2_); c2_ = dot2_(P3(w[2][i]), hp3, c2_); \
        c3_ = dot2_(P0(w[3][i]), hp0, c3_); c3_ = dot2_(P1(w[3][i]), hp1, c3_); \
        c3_ = dot2_(P2(w[3][i]), hp2, c3_); c3_ = dot2_(P3(w[3][i]), hp3, c3_); \
    }

    int p = 0;
    for (int t = 0; t < T_LEN; t++) {
        // ---- prefetch next-step xproj/done (hides under the dot loop) ----
        const int tn = (t + 1 < T_LEN) ? t + 1 : t;
        const float xqn = bias_l + xproj[((size_t)tn * B_ENV + b) * 512 + ci * 4 + s];
        const float dnn = done[tn * B_ENV + b];

        // ---- 64 dot2 in 8 independent chains ----
        float a0 = (s == 0) ? xq : 0.0f;
        float a1 = (s == 1) ? xq : 0.0f;
        float a2 = (s == 2) ? xq : 0.0f;
        float a3 = (s == 3) ? xq : 0.0f;
        float b0 = 0.f, b1 = 0.f, b2 = 0.f, b3 = 0.f;
        DOTBLK(0, a0, a1, a2, a3)
        DOTBLK(1, b0, b1, b2, b3)
        DOTBLK(2, a0, a1, a2, a3)
        DOTBLK(3, b0, b1, b2, b3)
        a0 += b0; a1 += b1; a2 += b2; a3 += b3;

        // ---- DPP quad butterfly (pure VALU, no LDS) ----
        a0 = bfly_sum4(a0); a1 = bfly_sum4(a1);
        a2 = bfly_sum4(a2); a3 = bfly_sum4(a3);

        // ---- fast activations + update (identical in all 4 lanes) ----
        const float gi = sigm_(a0), gf = sigm_(a1);
        const float gg = tanh_(a2), go = sigm_(a3);
        const float m = 1.0f - dcur;
        c = fmaf(gf, c * m, gi * gg);
        h = go * tanh_(c);

        if (s == 0) {
            hid16[((size_t)t * B_ENV + b) * HID + ci] = f2h(h);
            hbuf[p ^ 1][ci] = (_Float16)(h * (1.0f - dnn));
        }

        xq = xqn; dcur = dnn; p ^= 1;
        __syncthreads();
    }

    if (s == 0) {
        out[262144 + b * HID + ci] = h;
        out[294912 + b * HID + ci] = c;
    }
#undef DOTBLK
}

// ---------------------------------------------------------------------------
// K5: heads. out[n][0..6] = actor, out[n][7] = critic. 32 rows / block.
// ---------------------------------------------------------------------------
__global__ __launch_bounds__(256, 2) void heads_kernel(
    const unsigned short* __restrict__ hid16,
    const float* __restrict__ aw, const float* __restrict__ ab,
    const float* __restrict__ cw, const float* __restrict__ cb,
    float* __restrict__ out)
{
    __shared__ float hs[32 * 129];
    __shared__ float ws[8 * 130];
    __shared__ float bs[8];

    const int tid = threadIdx.x;
    const int n0 = blockIdx.x * 32;

    for (int i = tid; i < 1024; i += 256) {
        const int r = i >> 7, k = i & 127;
        ws[r * 130 + k] = (r < 7) ? aw[r * 128 + k] : cw[k];
    }
    if (tid < 8) bs[tid] = (tid < 7) ? ab[tid] : cb[0];
    // staged fp16 -> fp32 conversion, 8 halves per thread iteration
    for (int i = tid; i < 512; i += 256) {
        const int r = i >> 4, k8 = (i & 15) * 8;
        const ushort8v v = *(const ushort8v*)&hid16[(size_t)(n0 + r) * 128 + k8];
#pragma unroll
        for (int q = 0; q < 8; q++) {
            union { unsigned short u; _Float16 h; } un; un.u = v[q];
            hs[r * 129 + k8 + q] = (float)un.h;
        }
    }
    __syncthreads();

    const int r = tid >> 3, jj = tid & 7;
    float acc = bs[jj];
    const float* hp = &hs[r * 129];
    const float* wp = &ws[jj * 130];
#pragma unroll
    for (int k = 0; k < 128; k++) acc = fmaf(hp[k], wp[k], acc);
    out[(size_t)(n0 + r) * 8 + jj] = acc;
}

// ---------------------------------------------------------------------------
extern "C" void kernel_launch(void* const* d_in, const int* in_sizes, int n_in,
                              void* d_out, int out_size, void* d_ws, size_t ws_size,
                              hipStream_t stream)
{
    (void)in_sizes; (void)n_in; (void)out_size; (void)ws_size;

    const float* obs  = (const float*)d_in[0];
    const float* done = (const float*)d_in[1];
    const float* h0   = (const float*)d_in[2];
    const float* c0   = (const float*)d_in[3];
    const float* w1   = (const float*)d_in[4];
    const float* b1   = (const float*)d_in[5];
    const float* w2   = (const float*)d_in[6];
    const float* b2   = (const float*)d_in[7];
    const float* w3   = (const float*)d_in[8];
    const float* b3   = (const float*)d_in[9];
    const float* w_ih = (const float*)d_in[10];
    const float* w_hh = (const float*)d_in[11];
    const float* b_ih = (const float*)d_in[12];
    const float* b_hh = (const float*)d_in[13];
    const float* aw   = (const float*)d_in[14];
    const float* ab   = (const float*)d_in[15];
    const float* cw   = (const float*)d_in[16];
    const float* cb   = (const float*)d_in[17];
    float* out = (float*)d_out;

    unsigned short* featb = (unsigned short*)d_ws;     // 33,554,432 u16
    unsigned short* wb    = featb + 33554432ull;       //    524,288 u16
    unsigned short* wb2g  = wb    + 524288ull;         //      2,048 u16
    unsigned short* wb3g  = wb2g  + 2048ull;           //      8,192 u16
    float* xproj = (float*)(wb3g + 8192ull + 2048ull); // align pad; 16,777,216 f32
    unsigned short* hid16 = (unsigned short*)(xproj + 16777216ull); // 4,194,304 u16
    unsigned short* whhr  = hid16 + 4194304ull;        // 65,536 u16

    prep_all<<<2344, 256, 0, stream>>>(w_ih, wb, w2, w3, wb2g, wb3g, w_hh, whhr);
    conv_fused<<<2048, 256, 0, stream>>>(obs, w1, b1, b2, b3, wb2g, wb3g, featb);
    gemm_xproj_mfma<<<512, 512, 0, stream>>>(featb, wb, xproj);
    lstm_bfly<<<256, 512, 0, stream>>>(xproj, done, h0, c0, whhr, b_ih, b_hh, hid16, out);
    heads_kernel<<<1024, 256, 0, stream>>>(hid16, aw, ab, cw, cb, out);
}